// Round 11
// baseline (3359.368 us; speedup 1.0000x reference)
//
#include <hip/hip_runtime.h>

typedef _Float16 half8 __attribute__((ext_vector_type(8)));
typedef float f32x16 __attribute__((ext_vector_type(16)));
typedef unsigned long long u64;

#define SEQ 512
#define HID 1024
#define HB 65536  // elements per h slice / per x time-slice

// ---- LDS layout: 6 gate-partial buffers [64][36] f32 + arrive counter ----
// gX[pp][khalf] (4) then gH[khalf] (2). 2304 floats each.
#define GBUF_F 2304
#define LDS_ARR (6 * 9216)
#define LDS_TOTAL (6 * 9216 + 64)

__device__ __forceinline__ float sigf(float x) { return 1.0f / (1.0f + __expf(-x)); }
__device__ __forceinline__ float tanhfast(float x) {
  x = fminf(fmaxf(x, -44.0f), 44.0f);
  float e = __expf(2.0f * x);
  return (e - 1.0f) / (e + 1.0f);
}

// x (f32 [t][b][1024]) -> xh (f16 blocked [t][kc=128][b=64][cc=8]).
__global__ __launch_bounds__(256, 1) void cvt_blk(const float* __restrict__ in,
                                                  _Float16* __restrict__ out, int nItems) {
  int stride = gridDim.x * blockDim.x;
  for (int g = blockIdx.x * blockDim.x + threadIdx.x; g < nItems; g += stride) {
    int t = g >> 13;        // item = ((t*128 + kc)*64 + b)
    int r = g & 8191;
    int kc = r >> 6;
    int b = r & 63;
    const float* sp = in + (((size_t)t * 64 + b) << 10) + kc * 8;
    float4 v0 = *(const float4*)sp;
    float4 v1 = *(const float4*)(sp + 4);
    half8 o;
    o[0] = (_Float16)v0.x; o[1] = (_Float16)v0.y; o[2] = (_Float16)v0.z; o[3] = (_Float16)v0.w;
    o[4] = (_Float16)v1.x; o[5] = (_Float16)v1.y; o[6] = (_Float16)v1.z; o[7] = (_Float16)v1.w;
    ((half8*)out)[g] = o;
  }
}

// Poll 128 u32 flags (64 u64 words, one per lane) until min >= tgt.
__device__ __forceinline__ void pollFlags(const unsigned* f, unsigned tgt, int lane) {
  const u64* fp = (const u64*)f;
  for (;;) {
    u64 v = __hip_atomic_load(fp + lane, __ATOMIC_RELAXED, __HIP_MEMORY_SCOPE_AGENT);
    unsigned a = (unsigned)v, b = (unsigned)(v >> 32);
    unsigned mn = a < b ? a : b;
    if (__all(mn >= tgt)) break;
    __builtin_amdgcn_s_sleep(1);
  }
}

// [32 batch] x [32 gate] x K=512 GEMM, B from REGISTERS (bw[32], loop-invariant).
// A (blocked [kc][b][8]) via rotating 8-deep register window: 8 loads in flight.
__device__ __forceinline__ f32x16 gemm_reg(const _Float16* aPtr, const half8 (&bw)[32]) {
  f32x16 acc[4];
#pragma unroll
  for (int q = 0; q < 4; ++q)
#pragma unroll
    for (int i = 0; i < 16; ++i) acc[q][i] = 0.0f;

  half8 aw[8];
#pragma unroll
  for (int u = 0; u < 8; ++u) aw[u] = *(const half8*)(aPtr + u * 1024);
#pragma unroll
  for (int u = 0; u < 32; ++u) {
    acc[u & 3] = __builtin_amdgcn_mfma_f32_32x32x16_f16(aw[u & 7], bw[u], acc[u & 3], 0, 0, 0);
    if (u + 8 < 32) aw[u & 7] = *(const half8*)(aPtr + (u + 8) * 1024);
  }
  return acc[0] + acc[1] + acc[2] + acc[3];
}

__device__ __forceinline__ void writeGates(float* gbuf, const f32x16& t, int mtile, int lane) {
#pragma unroll
  for (int r = 0; r < 16; ++r) {
    int bl = (r & 3) + ((r >> 2) << 3) + ((lane >> 5) << 2);
    gbuf[(mtile * 32 + bl) * 36 + (lane & 31)] = t[r];
  }
}

// Persistent fused 2-layer LSTM. 256 WGs x 512 thr (8 waves).
// Wave roles: gsel = wave>>2 (0 input, 1 recurrent), khalf = (wave>>1)&1,
// mtile = wave&1. B slice (32 gate rows x K=512) lives in 128 VGPRs per wave,
// gathered once from global fp32 at prologue. Steady state: ZERO LDS B-reads.
// Gate partials -> 6 separate LDS buffers (no atomics): gX[pp][khalf], gH[khalf].
// h slices blocked [kc][b][8], write-once history; WT sc1 stores + drain;
// per-WG flag publish; flat flag polling. Same sync skeleton as R7/R10.
__global__ __launch_bounds__(512, 1) void lstm_fused(
    const _Float16* __restrict__ xh,
    const float* __restrict__ Wih0, const float* __restrict__ Whh0, const float* __restrict__ b0,
    const float* __restrict__ Wih1, const float* __restrict__ Whh1, const float* __restrict__ b1,
    _Float16* __restrict__ h0buf, _Float16* __restrict__ h1buf,
    unsigned* __restrict__ flags, float* __restrict__ out) {
  extern __shared__ char smem[];
  float* gbase = (float*)smem;
  unsigned* arrCnt = (unsigned*)(smem + LDS_ARR);

  const int tid = threadIdx.x;
  const int lane = tid & 63;
  const int wave = tid >> 6;
  const int gsel = wave >> 2;       // 0 = input GEMM, 1 = recurrent GEMM
  const int khalf = (wave >> 1) & 1;
  const int mtile = wave & 1;
  const int wg = blockIdx.x;
  const int layer = wg >> 7;
  const int lw = wg & 127;
  const int j0 = lw * 8;

  // ---- prologue: gather this wave's B slice into registers (fp32 -> fp16) ----
  const int brow = lane & 31;
  const int grow = ((brow >> 3) << 10) + j0 + (brow & 7);  // global gate row
  const float* wsrc = gsel ? (layer ? Whh1 : Whh0) : (layer ? Wih1 : Wih0);
  const float* rowp = wsrc + (size_t)grow * 1024 + khalf * 512 + ((lane >> 5) << 3);
  half8 bw[32];
#pragma unroll
  for (int ks = 0; ks < 32; ++ks) {
    float4 w0 = *(const float4*)(rowp + ks * 16);
    float4 w1 = *(const float4*)(rowp + ks * 16 + 4);
    half8 v;
    v[0] = (_Float16)w0.x; v[1] = (_Float16)w0.y; v[2] = (_Float16)w0.z; v[3] = (_Float16)w0.w;
    v[4] = (_Float16)w1.x; v[5] = (_Float16)w1.y; v[6] = (_Float16)w1.z; v[7] = (_Float16)w1.w;
    bw[ks] = v;
  }
  // bias -> registers (thread's epilogue gate column j = tid & 7)
  const float* bsrc = layer ? b1 : b0;
  const int jmy = tid & 7;
  const float bi_r = bsrc[j0 + jmy];
  const float bf_r = bsrc[1024 + j0 + jmy];
  const float bg_r = bsrc[2048 + j0 + jmy];
  const float bo_r = bsrc[3072 + j0 + jmy];
  float creg = 0.0f;  // cell state for item tid (512 items total)
  if (tid == 0) *arrCnt = 0u;
  __syncthreads();

  // per-wave constant addressing (blocked A layout; khalf K-offset)
  const int arow = mtile * 32 + (lane & 31);
  const int aoff = khalf * 32768 + ((lane >> 5) << 9) + arow * 8;
  _Float16* hSelf = layer ? h1buf : h0buf;
  const unsigned* flagsSelf = flags + (layer << 7);
  float* outy = out;
  float* outh = out + 33554432;
  float* outc = out + 33685504;

  // prologue phase A(0): input gates for step 0 -> gX[pp=0][khalf]
  if (gsel == 0) {
    if (layer) pollFlags(flags, 1u, lane);  // need h0 slice 1
    const _Float16* aB = layer ? (h0buf + (size_t)1 * HB) : xh;
    f32x16 t = gemm_reg(aB + aoff, bw);
    writeGates(gbase + khalf * GBUF_F, t, mtile, lane);
  }

  for (int k = 0; k < SEQ; ++k) {
    __syncthreads();  // epilogue k-1 fully done before buffer overwrite
    if (gsel == 0) {
      if (k + 1 < SEQ) {  // phase A(k+1) -> gX[(k+1)&1][khalf]
        if (layer) pollFlags(flags, (unsigned)(k + 2), lane);
        const _Float16* aB =
            layer ? (h0buf + (size_t)(k + 2) * HB) : (xh + (size_t)(k + 1) * HB);
        f32x16 t = gemm_reg(aB + aoff, bw);
        writeGates(gbase + (((k + 1) & 1) * 2 + khalf) * GBUF_F, t, mtile, lane);
      }
    } else {
      if (k > 0) pollFlags(flagsSelf, (unsigned)k, lane);  // own h slice k ready
      f32x16 t = gemm_reg(hSelf + (size_t)k * HB + aoff, bw);
      writeGates(gbase + (4 + khalf) * GBUF_F, t, mtile, lane);
    }
    __syncthreads();  // gX[k&1][*] (prev iter) + gH[*] complete

    // ---- epilogue step k: 512 threads x 1 item; sum 4 partial buffers ----
    const float* g0 = gbase + ((k & 1) * 2 + 0) * GBUF_F;  // gX khalf 0
    const float* g1 = gbase + ((k & 1) * 2 + 1) * GBUF_F;  // gX khalf 1
    const float* h0p = gbase + 4 * GBUF_F;                 // gH khalf 0
    const float* h1p = gbase + 5 * GBUF_F;                 // gH khalf 1
    u64* hw64 = (u64*)(hSelf + (size_t)(k + 1) * HB);
    const bool last = (k == SEQ - 1);
    int b = tid >> 3, j = tid & 7;
    int i0 = b * 36 + j;
    float vi = g0[i0] + g1[i0] + h0p[i0] + h1p[i0] + bi_r;
    float vf = g0[i0 + 8] + g1[i0 + 8] + h0p[i0 + 8] + h1p[i0 + 8] + bf_r;
    float vg = g0[i0 + 16] + g1[i0 + 16] + h0p[i0 + 16] + h1p[i0 + 16] + bg_r;
    float vo = g0[i0 + 24] + g1[i0 + 24] + h0p[i0 + 24] + h1p[i0 + 24] + bo_r;
    float i_ = sigf(vi), f_ = sigf(vf), g_ = tanhfast(vg), o_ = sigf(vo);
    float hn = o_ * tanhfast(creg);  // faithful: h uses PREVIOUS cell state
    float cn = f_ * creg + i_ * g_;
    creg = cn;
    // blocked h store: WG-owned contiguous 1KB region, full lines
    union { _Float16 h; unsigned short u; } hb; hb.h = (_Float16)hn;
    unsigned lo = (unsigned)hb.u;
    unsigned pr1 = (unsigned)__shfl_xor((int)lo, 1, 64);
    unsigned pk32 = lo | (pr1 << 16);
    u64 pr2 = (u64)(unsigned)__shfl_xor((int)pk32, 2, 64);
    if ((j & 3) == 0) {
      u64 v = (u64)pk32 | (pr2 << 32);
      __hip_atomic_store(hw64 + (lw * 64 + b) * 2 + (j >> 2), v, __ATOMIC_RELAXED,
                         __HIP_MEMORY_SCOPE_AGENT);
    }
    // release: per-wave drain + LDS arrive; 8th wave publishes flag k+1
    asm volatile("s_waitcnt vmcnt(0)" ::: "memory");
    if (lane == 0) {
      unsigned old = atomicAdd(arrCnt, 1u);
      if (old == 8u * (unsigned)k + 7u)
        __hip_atomic_store(&flags[wg], (unsigned)(k + 1), __ATOMIC_RELAXED,
                           __HIP_MEMORY_SCOPE_AGENT);
    }
    // y / final-state stores (off the release path, reference layout)
    int col = j0 + j;
    if (layer)
      __builtin_nontemporal_store(hn, &outy[(size_t)k * HB + b * HID + col]);
    if (last) {
      __builtin_nontemporal_store(hn, &outh[layer * HB + b * HID + col]);
      __builtin_nontemporal_store(cn, &outc[layer * HB + b * HID + col]);
    }
  }
}

extern "C" void kernel_launch(void* const* d_in, const int* in_sizes, int n_in,
                              void* d_out, int out_size, void* d_ws, size_t ws_size,
                              hipStream_t stream) {
  const float* x = (const float*)d_in[0];
  const float* Wih0 = (const float*)d_in[1];
  const float* Whh0 = (const float*)d_in[2];
  const float* b0 = (const float*)d_in[3];
  const float* Wih1 = (const float*)d_in[4];
  const float* Whh1 = (const float*)d_in[5];
  const float* b1 = (const float*)d_in[6];
  float* out = (float*)d_out;

  char* ws = (char*)d_ws;
  _Float16* xh = (_Float16*)ws;                    // 512 x 131072 B (blocked)
  _Float16* h0 = (_Float16*)(ws + 67108864);       // 513 slices x 131072 B (blocked)
  _Float16* h1 = (_Float16*)(ws + 134348800);      // 513 slices x 131072 B (blocked)
  unsigned* flags = (unsigned*)(ws + 201588736);   // 256 u32

  hipMemsetAsync(h0, 0, 131072, stream);
  hipMemsetAsync(h1, 0, 131072, stream);
  hipMemsetAsync(flags, 0, 1024, stream);
  cvt_blk<<<4096, 256, 0, stream>>>(x, xh, 512 * 128 * 64);
  lstm_fused<<<256, 512, LDS_TOTAL, stream>>>(xh, Wih0, Whh0, b0, Wih1, Whh1, b1,
                                              h0, h1, flags, out);
}

// Round 12
// 3120.942 us; speedup vs baseline: 1.0764x; 1.0764x over previous
//
#include <hip/hip_runtime.h>

typedef _Float16 half8 __attribute__((ext_vector_type(8)));
typedef float f32x16 __attribute__((ext_vector_type(16)));
typedef unsigned long long u64;

#define SEQ 512
#define HID 1024
#define HB 65536  // elements per h slice / per x time-slice

// ---- LDS layout (bytes) ----
#define WROW 2064  // 2048 B data + 16 B pad -> conflict-free ds_read_b128
#define LDS_WIH 0        // 32 rows x 2064
#define LDS_WHH 66048    // 32 rows x 2064
#define LDS_GX0 132096   // [64][36] f32 (input-gate partials, ping)
#define LDS_GX1 141312   // [64][36] f32 (pong)
#define LDS_GH  150528   // [64][36] f32 (recurrent partials)
#define LDS_ARR 159744   // arrive counter
#define LDS_TOTAL 159808

__device__ __forceinline__ float sigf(float x) { return 1.0f / (1.0f + __expf(-x)); }
__device__ __forceinline__ float tanhfast(float x) {
  x = fminf(fmaxf(x, -44.0f), 44.0f);
  float e = __expf(2.0f * x);
  return (e - 1.0f) / (e + 1.0f);
}

// x (f32 [t][b][1024]) -> xh (f16 blocked [t][kc=128][b=64][cc=8]).
__global__ __launch_bounds__(256, 1) void cvt_blk(const float* __restrict__ in,
                                                  _Float16* __restrict__ out, int nItems) {
  int stride = gridDim.x * blockDim.x;
  for (int g = blockIdx.x * blockDim.x + threadIdx.x; g < nItems; g += stride) {
    int t = g >> 13;        // item = ((t*128 + kc)*64 + b)
    int r = g & 8191;
    int kc = r >> 6;
    int b = r & 63;
    const float* sp = in + (((size_t)t * 64 + b) << 10) + kc * 8;
    float4 v0 = *(const float4*)sp;
    float4 v1 = *(const float4*)(sp + 4);
    half8 o;
    o[0] = (_Float16)v0.x; o[1] = (_Float16)v0.y; o[2] = (_Float16)v0.z; o[3] = (_Float16)v0.w;
    o[4] = (_Float16)v1.x; o[5] = (_Float16)v1.y; o[6] = (_Float16)v1.z; o[7] = (_Float16)v1.w;
    ((half8*)out)[g] = o;
  }
}

// Poll 128 u32 flags (64 u64 words, one per lane) until min >= tgt.
__device__ __forceinline__ void pollFlags(const unsigned* f, unsigned tgt, int lane) {
  const u64* fp = (const u64*)f;
  for (;;) {
    u64 v = __hip_atomic_load(fp + lane, __ATOMIC_RELAXED, __HIP_MEMORY_SCOPE_AGENT);
    unsigned a = (unsigned)v, b = (unsigned)(v >> 32);
    unsigned mn = a < b ? a : b;
    if (__all(mn >= tgt)) break;
    __builtin_amdgcn_s_sleep(1);
  }
}

// One wave's [32 batch] x [32 gate] x K=1024 GEMM over BLOCKED A ([kc][b][8]).
// ASM-FORCED 32-deep rolling A window: global_load_dwordx4 with "=v" outputs
// cannot be sunk or shrunk by RA -> 32 KB in flight per wave. Counted
// s_waitcnt vmcnt(N) retires exactly the group being consumed (verified:
// waits 24,24,24,24,24,16,8,0). sched_barrier(0) after each wait per rule #18
// (compiler may otherwise hoist register-only MFMAs past the asm waitcnt).
// Entry vmcnt(0) zeroes the counter (prior y-stores would skew counts).
// B: LDS fp16 rows, stride 2064 B (conflict-free b128).
__device__ __forceinline__ f32x16 gemm_asm(const _Float16* aPtr, const char* wB, int bsub) {
  f32x16 acc[4];
#pragma unroll
  for (int q = 0; q < 4; ++q)
#pragma unroll
    for (int i = 0; i < 16; ++i) acc[q][i] = 0.0f;

  half8 aw[32];
  asm volatile("s_waitcnt vmcnt(0)" ::: "memory");
#pragma unroll
  for (int u = 0; u < 32; ++u)
    asm volatile("global_load_dwordx4 %0, %1, off"
                 : "=v"(aw[u]) : "v"(aPtr + u * 1024) : "memory");

  half8 bw[8];
#pragma unroll
  for (int w = 0; w < 8; ++w) {
    // B reads for this group issue before the A-wait (overlap)
#pragma unroll
    for (int u = 0; u < 8; ++u)
      bw[u] = *(const half8*)(wB + (w * 8 + u) * 32 + bsub);
    if (w < 5)       asm volatile("s_waitcnt vmcnt(24)" ::: "memory");
    else if (w == 5) asm volatile("s_waitcnt vmcnt(16)" ::: "memory");
    else if (w == 6) asm volatile("s_waitcnt vmcnt(8)" ::: "memory");
    else             asm volatile("s_waitcnt vmcnt(0)" ::: "memory");
    __builtin_amdgcn_sched_barrier(0);
#pragma unroll
    for (int u = 0; u < 8; ++u)
      acc[u & 3] = __builtin_amdgcn_mfma_f32_32x32x16_f16(aw[(w & 3) * 8 + u], bw[u],
                                                          acc[u & 3], 0, 0, 0);
    if (w < 4) {
#pragma unroll
      for (int u = 0; u < 8; ++u)
        asm volatile("global_load_dwordx4 %0, %1, off"
                     : "=v"(aw[(w & 3) * 8 + u])
                     : "v"(aPtr + (32 + w * 8 + u) * 1024) : "memory");
    }
  }
  return acc[0] + acc[1] + acc[2] + acc[3];
}

__device__ __forceinline__ void writeGates(float* gbuf, const f32x16& t, int mtile, int lane) {
#pragma unroll
  for (int r = 0; r < 16; ++r) {
    int bl = (r & 3) + ((r >> 2) << 3) + ((lane >> 5) << 2);
    gbuf[(mtile * 32 + bl) * 36 + (lane & 31)] = t[r];
  }
}

// Persistent fused 2-layer LSTM (R7/R10 structure). WGs 0..127 layer0, 128..255 layer1.
// Waves 0,1 = input GEMM (phase A, step k+1); waves 2,3 = recurrent (step k).
// h slices blocked [kc][b][8]: WG w fully owns block kc=w&127 -> full-line WT
// stores, coalesced A reads. Flat flag barrier; y-stores off the release path.
__global__ __launch_bounds__(256, 1) void lstm_fused(
    const _Float16* __restrict__ xh,
    const float* __restrict__ Wih0, const float* __restrict__ Whh0, const float* __restrict__ b0,
    const float* __restrict__ Wih1, const float* __restrict__ Whh1, const float* __restrict__ b1,
    _Float16* __restrict__ h0buf, _Float16* __restrict__ h1buf,
    unsigned* __restrict__ flags, float* __restrict__ out) {
  extern __shared__ char smem[];
  float* gH = (float*)(smem + LDS_GH);
  unsigned* arrCnt = (unsigned*)(smem + LDS_ARR);

  const int tid = threadIdx.x;
  const int lane = tid & 63;
  const int wave = tid >> 6;
  const int mtile = wave & 1;   // which 32 batches
  const int gsel = wave >> 1;   // 0 = input waves, 1 = recurrent waves
  const int wg = blockIdx.x;
  const int layer = wg >> 7;
  const int lw = wg & 127;
  const int j0 = lw * 8;

  // ---- prologue: stage W slices (fp32 global -> fp16 LDS) ----
  const float* wsrc0 = layer ? Wih1 : Wih0;
  const float* wsrc1 = layer ? Whh1 : Whh0;
  for (int m = 0; m < 2; ++m) {
    const float* src = m ? wsrc1 : wsrc0;
    char* base = smem + (m ? LDS_WHH : LDS_WIH);
    for (int q = tid; q < 4096; q += 256) {
      int r = q >> 7;               // local gate row 0..31
      int kc = (q & 127) << 3;      // k chunk base (elements)
      int grow = ((r >> 3) << 10) + j0 + (r & 7);  // global gate row
      const float* sp = src + (size_t)grow * 1024 + kc;
      half8 v;
#pragma unroll
      for (int j = 0; j < 8; ++j) v[j] = (_Float16)sp[j];
      *(half8*)(base + r * WROW + kc * 2) = v;
    }
  }
  // bias -> registers (thread's gate column j = tid & 7 is fixed)
  const float* bsrc = layer ? b1 : b0;
  const int jmy = tid & 7;
  const float bi_r = bsrc[j0 + jmy];
  const float bf_r = bsrc[1024 + j0 + jmy];
  const float bg_r = bsrc[2048 + j0 + jmy];
  const float bo_r = bsrc[3072 + j0 + jmy];
  float creg[2] = {0.0f, 0.0f};  // cell state for items tid, tid+256
  if (tid == 0) *arrCnt = 0u;
  __syncthreads();

  // per-wave constant addressing (blocked A layout)
  const int arow = mtile * 32 + (lane & 31);          // batch row
  const int aoff = ((lane >> 5) << 9) + arow * 8;     // k-half sub-block + batch
  const int brow = lane & 31;                          // gate row for B fragment
  const int bsub = (lane >> 5) << 4;                   // k sub-offset (bytes)
  const char* wIH = smem + LDS_WIH + brow * WROW;
  const char* wHH = smem + LDS_WHH + brow * WROW;
  _Float16* hSelf = layer ? h1buf : h0buf;
  const unsigned* flagsSelf = flags + (layer << 7);
  float* outy = out;
  float* outh = out + 33554432;
  float* outc = out + 33685504;

  // prologue phase A(0): input gates for step 0 -> gX0
  if (gsel == 0) {
    if (layer) pollFlags(flags, 1u, lane);  // need h0 slice 1 (= y0 of t=0)
    const _Float16* aB = layer ? (h0buf + (size_t)1 * HB) : xh;
    f32x16 t = gemm_asm(aB + aoff, wIH, bsub);
    writeGates((float*)(smem + LDS_GX0), t, mtile, lane);
  }

  for (int k = 0; k < SEQ; ++k) {
    __syncthreads();  // epilogue k-1 fully done before gH/gX overwrite
    if (gsel == 0) {
      if (k + 1 < SEQ) {  // phase A(k+1)
        if (layer) pollFlags(flags, (unsigned)(k + 2), lane);
        const _Float16* aB =
            layer ? (h0buf + (size_t)(k + 2) * HB) : (xh + (size_t)(k + 1) * HB);
        f32x16 t = gemm_asm(aB + aoff, wIH, bsub);
        writeGates((float*)(smem + ((k + 1) & 1 ? LDS_GX1 : LDS_GX0)), t, mtile, lane);
      }
    } else {
      if (k > 0) pollFlags(flagsSelf, (unsigned)k, lane);  // own h slice k ready
      f32x16 t = gemm_asm(hSelf + (size_t)k * HB + aoff, wHH, bsub);
      writeGates(gH, t, mtile, lane);
    }
    __syncthreads();  // gX[k&1] (prev iter / prologue) + gH complete

    // ---- epilogue step k (all 256 threads, 2 items each) ----
    const float* gX = (const float*)(smem + ((k & 1) ? LDS_GX1 : LDS_GX0));
    u64* hw64 = (u64*)(hSelf + (size_t)(k + 1) * HB);
    const bool last = (k == SEQ - 1);
    float hnv[2], cnv[2];
#pragma unroll
    for (int it = 0; it < 2; ++it) {
      int item = tid + it * 256;
      int b = item >> 3, j = item & 7;
      float vi = gX[b * 36 + j] + gH[b * 36 + j] + bi_r;
      float vf = gX[b * 36 + 8 + j] + gH[b * 36 + 8 + j] + bf_r;
      float vg = gX[b * 36 + 16 + j] + gH[b * 36 + 16 + j] + bg_r;
      float vo = gX[b * 36 + 24 + j] + gH[b * 36 + 24 + j] + bo_r;
      float i_ = sigf(vi), f_ = sigf(vf), g_ = tanhfast(vg), o_ = sigf(vo);
      float cp = creg[it];
      float hn = o_ * tanhfast(cp);  // faithful: h uses PREVIOUS cell state
      float cn = f_ * cp + i_ * g_;
      creg[it] = cn;
      hnv[it] = hn; cnv[it] = cn;
      // blocked h store: WG-owned contiguous 1KB region, full lines
      union { _Float16 h; unsigned short u; } hb; hb.h = (_Float16)hn;
      unsigned lo = (unsigned)hb.u;
      unsigned pr1 = (unsigned)__shfl_xor((int)lo, 1, 64);
      unsigned pk32 = lo | (pr1 << 16);
      u64 pr2 = (u64)(unsigned)__shfl_xor((int)pk32, 2, 64);
      if ((j & 3) == 0) {
        u64 v = (u64)pk32 | (pr2 << 32);
        __hip_atomic_store(hw64 + (lw * 64 + b) * 2 + (j >> 2), v, __ATOMIC_RELAXED,
                           __HIP_MEMORY_SCOPE_AGENT);
      }
    }
    // release: per-wave drain + LDS arrive; last wave publishes flag k+1
    asm volatile("s_waitcnt vmcnt(0)" ::: "memory");
    if (lane == 0) {
      unsigned old = atomicAdd(arrCnt, 1u);
      if (old == 4u * (unsigned)k + 3u)
        __hip_atomic_store(&flags[wg], (unsigned)(k + 1), __ATOMIC_RELAXED,
                           __HIP_MEMORY_SCOPE_AGENT);
    }
    // y / final-state stores (off the release path, reference layout)
#pragma unroll
    for (int it = 0; it < 2; ++it) {
      int item = tid + it * 256;
      int b = item >> 3, j = item & 7;
      int col = j0 + j;
      if (layer)
        __builtin_nontemporal_store(hnv[it], &outy[(size_t)k * HB + b * HID + col]);
      if (last) {
        __builtin_nontemporal_store(hnv[it], &outh[layer * HB + b * HID + col]);
        __builtin_nontemporal_store(cnv[it], &outc[layer * HB + b * HID + col]);
      }
    }
  }
}

extern "C" void kernel_launch(void* const* d_in, const int* in_sizes, int n_in,
                              void* d_out, int out_size, void* d_ws, size_t ws_size,
                              hipStream_t stream) {
  const float* x = (const float*)d_in[0];
  const float* Wih0 = (const float*)d_in[1];
  const float* Whh0 = (const float*)d_in[2];
  const float* b0 = (const float*)d_in[3];
  const float* Wih1 = (const float*)d_in[4];
  const float* Whh1 = (const float*)d_in[5];
  const float* b1 = (const float*)d_in[6];
  float* out = (float*)d_out;

  char* ws = (char*)d_ws;
  _Float16* xh = (_Float16*)ws;                    // 512 x 131072 B (blocked)
  _Float16* h0 = (_Float16*)(ws + 67108864);       // 513 slices x 131072 B (blocked)
  _Float16* h1 = (_Float16*)(ws + 134348800);      // 513 slices x 131072 B (blocked)
  unsigned* flags = (unsigned*)(ws + 201588736);   // 256 u32

  hipMemsetAsync(h0, 0, 131072, stream);
  hipMemsetAsync(h1, 0, 131072, stream);
  hipMemsetAsync(flags, 0, 1024, stream);
  cvt_blk<<<4096, 256, 0, stream>>>(x, xh, 512 * 128 * 64);
  lstm_fused<<<256, 256, LDS_TOTAL, stream>>>(xh, Wih0, Whh0, b0, Wih1, Whh1, b1,
                                              h0, h1, flags, out);
}

// Round 17
// 2837.698 us; speedup vs baseline: 1.1838x; 1.0998x over previous
//
#include <hip/hip_runtime.h>

typedef _Float16 half8 __attribute__((ext_vector_type(8)));
typedef float f32x16 __attribute__((ext_vector_type(16)));
typedef unsigned long long u64;

#define SEQ 512
#define HID 1024
#define HB 65536  // elements per h slice / per x time-slice

// ---- LDS layout (bytes) ----
#define WROW 2064  // 2048 B data + 16 B pad -> conflict-free ds_read_b128
#define LDS_WIH 0        // 32 rows x 2064
#define LDS_WHH 66048    // 32 rows x 2064
#define LDS_GX0 132096   // [64][36] f32 (input-gate partials, ping)
#define LDS_GX1 141312   // [64][36] f32 (pong)
#define LDS_GH  150528   // [64][36] f32 (recurrent partials)
#define LDS_ARR 159744   // arrive counter
#define LDS_TOTAL 159808

__device__ __forceinline__ float sigf(float x) { return 1.0f / (1.0f + __expf(-x)); }
__device__ __forceinline__ float tanhfast(float x) {
  x = fminf(fmaxf(x, -44.0f), 44.0f);
  float e = __expf(2.0f * x);
  return (e - 1.0f) / (e + 1.0f);
}

// x (f32 [t][b][1024]) -> xh (f16 blocked [t][kc=128][b=64][cc=8]).
__global__ __launch_bounds__(256, 1) void cvt_blk(const float* __restrict__ in,
                                                  _Float16* __restrict__ out, int nItems) {
  int stride = gridDim.x * blockDim.x;
  for (int g = blockIdx.x * blockDim.x + threadIdx.x; g < nItems; g += stride) {
    int t = g >> 13;        // item = ((t*128 + kc)*64 + b)
    int r = g & 8191;
    int kc = r >> 6;
    int b = r & 63;
    const float* sp = in + (((size_t)t * 64 + b) << 10) + kc * 8;
    float4 v0 = *(const float4*)sp;
    float4 v1 = *(const float4*)(sp + 4);
    half8 o;
    o[0] = (_Float16)v0.x; o[1] = (_Float16)v0.y; o[2] = (_Float16)v0.z; o[3] = (_Float16)v0.w;
    o[4] = (_Float16)v1.x; o[5] = (_Float16)v1.y; o[6] = (_Float16)v1.z; o[7] = (_Float16)v1.w;
    ((half8*)out)[g] = o;
  }
}

// Poll 128 u32 flags (64 u64 words, one per lane) until min >= tgt.
__device__ __forceinline__ void pollFlags(const unsigned* f, unsigned tgt, int lane) {
  const u64* fp = (const u64*)f;
  for (;;) {
    u64 v = __hip_atomic_load(fp + lane, __ATOMIC_RELAXED, __HIP_MEMORY_SCOPE_AGENT);
    unsigned a = (unsigned)v, b = (unsigned)(v >> 32);
    unsigned mn = a < b ? a : b;
    if (__all(mn >= tgt)) break;
    __builtin_amdgcn_s_sleep(1);
  }
  asm volatile("" ::: "memory");  // no hoisting of dependent reads above the poll
}

// Local (intra-CU) wait: LDS arrive counter >= tgt. Replaces the global top
// barrier for input waves -- cheap LDS spin instead of full WG barrier+drain.
__device__ __forceinline__ void waitArr(unsigned* arrCnt, unsigned tgt) {
  for (;;) {
    unsigned v = __hip_atomic_load(arrCnt, __ATOMIC_RELAXED, __HIP_MEMORY_SCOPE_WORKGROUP);
    if (v >= tgt) break;
    __builtin_amdgcn_s_sleep(1);
  }
  asm volatile("" ::: "memory");
}

// One wave's [32 batch] x [32 gate] x K=1024 GEMM over BLOCKED A ([kc][b][8]).
// First 32 A-loads clustered via sched_group_barrier(VMEM_READ,32) (R10-best).
// B: LDS fp16 rows, stride 2064 B (conflict-free b128).
__device__ __forceinline__ f32x16 gemm_k(const _Float16* aPtr, const char* wB, int bsub) {
  f32x16 acc[4];
#pragma unroll
  for (int q = 0; q < 4; ++q)
#pragma unroll
    for (int i = 0; i < 16; ++i) acc[q][i] = 0.0f;

  half8 aw[64];
#pragma unroll
  for (int u = 0; u < 32; ++u) aw[u] = *(const half8*)(aPtr + u * 1024);
  __builtin_amdgcn_sched_group_barrier(0x20 /*VMEM_READ*/, 32, 0);
#pragma unroll
  for (int u = 32; u < 64; ++u) aw[u] = *(const half8*)(aPtr + u * 1024);

  half8 bw[8];
#pragma unroll
  for (int w = 0; w < 8; ++w) {
#pragma unroll
    for (int u = 0; u < 8; ++u)
      bw[u] = *(const half8*)(wB + (w * 8 + u) * 32 + bsub);
#pragma unroll
    for (int u = 0; u < 8; ++u)
      acc[u & 3] = __builtin_amdgcn_mfma_f32_32x32x16_f16(aw[w * 8 + u], bw[u],
                                                          acc[u & 3], 0, 0, 0);
  }
  return acc[0] + acc[1] + acc[2] + acc[3];
}

__device__ __forceinline__ void writeGates(float* gbuf, const f32x16& t, int mtile, int lane) {
#pragma unroll
  for (int r = 0; r < 16; ++r) {
    int bl = (r & 3) + ((r >> 2) << 3) + ((lane >> 5) << 2);
    gbuf[(mtile * 32 + bl) * 36 + (lane & 31)] = t[r];
  }
}

// Persistent fused 2-layer LSTM (R10 structure, ONE barrier per step).
// WGs 0..127 layer0, 128..255 layer1. Waves 0,1 = input GEMM (step k+1);
// waves 2,3 = recurrent (step k). Top barrier replaced by targeted gates:
// rec's global flag poll (flags>=k implies own-WG epilogue k-1 arrived) and
// input's LDS arrCnt spin (>=4k). One __syncthreads per step remains
// (gH/gX writes -> epilogue reads).
__global__ __launch_bounds__(256, 1) void lstm_fused(
    const _Float16* __restrict__ xh,
    const float* __restrict__ Wih0, const float* __restrict__ Whh0, const float* __restrict__ b0,
    const float* __restrict__ Wih1, const float* __restrict__ Whh1, const float* __restrict__ b1,
    _Float16* __restrict__ h0buf, _Float16* __restrict__ h1buf,
    unsigned* __restrict__ flags, float* __restrict__ out) {
  extern __shared__ char smem[];
  float* gH = (float*)(smem + LDS_GH);
  unsigned* arrCnt = (unsigned*)(smem + LDS_ARR);

  const int tid = threadIdx.x;
  const int lane = tid & 63;
  const int wave = tid >> 6;
  const int mtile = wave & 1;   // which 32 batches
  const int gsel = wave >> 1;   // 0 = input waves, 1 = recurrent waves
  const int wg = blockIdx.x;
  const int layer = wg >> 7;
  const int lw = wg & 127;
  const int j0 = lw * 8;

  // ---- prologue: stage W slices (fp32 global -> fp16 LDS) ----
  const float* wsrc0 = layer ? Wih1 : Wih0;
  const float* wsrc1 = layer ? Whh1 : Whh0;
  for (int m = 0; m < 2; ++m) {
    const float* src = m ? wsrc1 : wsrc0;
    char* base = smem + (m ? LDS_WHH : LDS_WIH);
    for (int q = tid; q < 4096; q += 256) {
      int r = q >> 7;               // local gate row 0..31
      int kc = (q & 127) << 3;      // k chunk base (elements)
      int grow = ((r >> 3) << 10) + j0 + (r & 7);  // global gate row
      const float* sp = src + (size_t)grow * 1024 + kc;
      half8 v;
#pragma unroll
      for (int j = 0; j < 8; ++j) v[j] = (_Float16)sp[j];
      *(half8*)(base + r * WROW + kc * 2) = v;
    }
  }
  // bias -> registers (thread's gate column j = tid & 7 is fixed)
  const float* bsrc = layer ? b1 : b0;
  const int jmy = tid & 7;
  const float bi_r = bsrc[j0 + jmy];
  const float bf_r = bsrc[1024 + j0 + jmy];
  const float bg_r = bsrc[2048 + j0 + jmy];
  const float bo_r = bsrc[3072 + j0 + jmy];
  float creg[2] = {0.0f, 0.0f};  // cell state for items tid, tid+256
  if (tid == 0) *arrCnt = 0u;
  __syncthreads();

  // per-wave constant addressing (blocked A layout)
  const int arow = mtile * 32 + (lane & 31);          // batch row
  const int aoff = ((lane >> 5) << 9) + arow * 8;     // k-half sub-block + batch
  const int brow = lane & 31;                          // gate row for B fragment
  const int bsub = (lane >> 5) << 4;                   // k sub-offset (bytes)
  const char* wIH = smem + LDS_WIH + brow * WROW;
  const char* wHH = smem + LDS_WHH + brow * WROW;
  _Float16* hSelf = layer ? h1buf : h0buf;
  const unsigned* flagsSelf = flags + (layer << 7);
  float* outy = out;
  float* outh = out + 33554432;
  float* outc = out + 33685504;

  // prologue phase A(0): input gates for step 0 -> gX0
  if (gsel == 0) {
    if (layer) pollFlags(flags, 1u, lane);  // need h0 slice 1 (= y0 of t=0)
    const _Float16* aB = layer ? (h0buf + (size_t)1 * HB) : xh;
    f32x16 t = gemm_k(aB + aoff, wIH, bsub);
    writeGates((float*)(smem + LDS_GX0), t, mtile, lane);
  }

  for (int k = 0; k < SEQ; ++k) {
    if (gsel == 0) {
      if (k + 1 < SEQ) {  // phase A(k+1)
        // wait: epilogue k-1 finished reading gX[(k+1)&1] (all 4 waves arrived)
        waitArr(arrCnt, 4u * (unsigned)k);
        if (layer) pollFlags(flags, (unsigned)(k + 2), lane);
        const _Float16* aB =
            layer ? (h0buf + (size_t)(k + 2) * HB) : (xh + (size_t)(k + 1) * HB);
        f32x16 t = gemm_k(aB + aoff, wIH, bsub);
        writeGates((float*)(smem + ((k + 1) & 1 ? LDS_GX1 : LDS_GX0)), t, mtile, lane);
      }
    } else {
      // flags >= k implies own-WG epilogue k-1 arrived -> gH free to overwrite
      if (k > 0) pollFlags(flagsSelf, (unsigned)k, lane);  // own h slice k ready
      f32x16 t = gemm_k(hSelf + (size_t)k * HB + aoff, wHH, bsub);
      writeGates(gH, t, mtile, lane);
    }
    __syncthreads();  // gX[k&1] (prev iter / prologue) + gH complete

    // ---- epilogue step k (all 256 threads, 2 items each) ----
    const float* gX = (const float*)(smem + ((k & 1) ? LDS_GX1 : LDS_GX0));
    u64* hw64 = (u64*)(hSelf + (size_t)(k + 1) * HB);
    const bool last = (k == SEQ - 1);
    float hnv[2], cnv[2];
#pragma unroll
    for (int it = 0; it < 2; ++it) {
      int item = tid + it * 256;
      int b = item >> 3, j = item & 7;
      float vi = gX[b * 36 + j] + gH[b * 36 + j] + bi_r;
      float vf = gX[b * 36 + 8 + j] + gH[b * 36 + 8 + j] + bf_r;
      float vg = gX[b * 36 + 16 + j] + gH[b * 36 + 16 + j] + bg_r;
      float vo = gX[b * 36 + 24 + j] + gH[b * 36 + 24 + j] + bo_r;
      float i_ = sigf(vi), f_ = sigf(vf), g_ = tanhfast(vg), o_ = sigf(vo);
      float cp = creg[it];
      float hn = o_ * tanhfast(cp);  // faithful: h uses PREVIOUS cell state
      float cn = f_ * cp + i_ * g_;
      creg[it] = cn;
      hnv[it] = hn; cnv[it] = cn;
      // blocked h store: WG-owned contiguous 1KB region, full lines
      union { _Float16 h; unsigned short u; } hb; hb.h = (_Float16)hn;
      unsigned lo = (unsigned)hb.u;
      unsigned pr1 = (unsigned)__shfl_xor((int)lo, 1, 64);
      unsigned pk32 = lo | (pr1 << 16);
      u64 pr2 = (u64)(unsigned)__shfl_xor((int)pk32, 2, 64);
      if ((j & 3) == 0) {
        u64 v = (u64)pk32 | (pr2 << 32);
        __hip_atomic_store(hw64 + (lw * 64 + b) * 2 + (j >> 2), v, __ATOMIC_RELAXED,
                           __HIP_MEMORY_SCOPE_AGENT);
      }
    }
    // release: per-wave drain + LDS arrive; last wave publishes flag k+1
    asm volatile("s_waitcnt vmcnt(0)" ::: "memory");
    if (lane == 0) {
      unsigned old = atomicAdd(arrCnt, 1u);
      if (old == 4u * (unsigned)k + 3u)
        __hip_atomic_store(&flags[wg], (unsigned)(k + 1), __ATOMIC_RELAXED,
                           __HIP_MEMORY_SCOPE_AGENT);
    }
    // y / final-state stores (off the release path, reference layout)
#pragma unroll
    for (int it = 0; it < 2; ++it) {
      int item = tid + it * 256;
      int b = item >> 3, j = item & 7;
      int col = j0 + j;
      if (layer)
        __builtin_nontemporal_store(hnv[it], &outy[(size_t)k * HB + b * HID + col]);
      if (last) {
        __builtin_nontemporal_store(hnv[it], &outh[layer * HB + b * HID + col]);
        __builtin_nontemporal_store(cnv[it], &outc[layer * HB + b * HID + col]);
      }
    }
  }
}

extern "C" void kernel_launch(void* const* d_in, const int* in_sizes, int n_in,
                              void* d_out, int out_size, void* d_ws, size_t ws_size,
                              hipStream_t stream) {
  const float* x = (const float*)d_in[0];
  const float* Wih0 = (const float*)d_in[1];
  const float* Whh0 = (const float*)d_in[2];
  const float* b0 = (const float*)d_in[3];
  const float* Wih1 = (const float*)d_in[4];
  const float* Whh1 = (const float*)d_in[5];
  const float* b1 = (const float*)d_in[6];
  float* out = (float*)d_out;

  char* ws = (char*)d_ws;
  _Float16* xh = (_Float16*)ws;                    // 512 x 131072 B (blocked)
  _Float16* h0 = (_Float16*)(ws + 67108864);       // 513 slices x 131072 B (blocked)
  _Float16* h1 = (_Float16*)(ws + 134348800);      // 513 slices x 131072 B (blocked)
  unsigned* flags = (unsigned*)(ws + 201588736);   // 256 u32

  hipMemsetAsync(h0, 0, 131072, stream);
  hipMemsetAsync(h1, 0, 131072, stream);
  hipMemsetAsync(flags, 0, 1024, stream);
  cvt_blk<<<4096, 256, 0, stream>>>(x, xh, 512 * 128 * 64);
  lstm_fused<<<256, 256, LDS_TOTAL, stream>>>(xh, Wih0, Whh0, b0, Wih1, Whh1, b1,
                                              h0, h1, flags, out);
}